// Round 9
// baseline (1196.703 us; speedup 1.0000x reference)
//
#include <hip/hip_runtime.h>
#include <hip/hip_bf16.h>
#include <cstdio>

#define N_P   65536
#define N_E   524288
#define RIG_  4096

typedef __attribute__((ext_vector_type(8))) short bf16x8;
typedef __attribute__((ext_vector_type(4))) float f32x4;
typedef unsigned short u16;
typedef unsigned int   u32;
typedef __attribute__((ext_vector_type(4))) u32 u32x4;

#define SLABN 2176            // 16 rows * 136 u16 per wave slab

__device__ __forceinline__ u16 f2b(float x) {
    __hip_bfloat16 h = __float2bfloat16(x);
    return *(u16*)&h;
}
__device__ __forceinline__ float b2f(u16 u) {
    union { unsigned u; float f; } c; c.u = ((unsigned)u) << 16; return c.f;
}
__device__ __forceinline__ unsigned pk2(float x, float y) {
    return (unsigned)f2b(x) | ((unsigned)f2b(y) << 16);
}
__device__ __forceinline__ uint2 pk4(float a, float b, float c, float d) {
    uint2 r; r.x = pk2(a, b); r.y = pk2(c, d); return r;
}
#define MFMA(a,b,c) __builtin_amdgcn_mfma_f32_16x16x32_bf16((a),(b),(c),0,0,0)

// K=128 layer, in-place on a wave-private slab (frag layout), weights as A-operand.
__device__ __forceinline__ void layer_inplace(u16* SLAB, int mm, int quad,
        const u16* __restrict__ wb, const float* __restrict__ bias) {
    f32x4 acc[8] = {};
    #pragma unroll
    for (int kc = 0; kc < 4; kc++) {
        bf16x8 xf = *(const bf16x8*)&SLAB[((kc * 4 + quad) * 16 + mm) * 8];
        #pragma unroll
        for (int nt = 0; nt < 8; nt++) {
            bf16x8 wf = *(const bf16x8*)(wb + (size_t)(nt * 16 + mm) * 128 + kc * 32 + quad * 8);
            acc[nt] = MFMA(wf, xf, acc[nt]);
        }
    }
    #pragma unroll
    for (int nt = 0; nt < 8; nt++) {
        float4 bb = *(const float4*)(bias + nt * 16 + quad * 4);
        *(uint2*)&SLAB[(((nt * 2 + (quad >> 1)) * 16 + mm) * 8) + (quad & 1) * 4] =
            pk4(fmaxf(acc[nt][0] + bb.x, 0.f), fmaxf(acc[nt][1] + bb.y, 0.f),
                fmaxf(acc[nt][2] + bb.z, 0.f), fmaxf(acc[nt][3] + bb.w, 0.f));
    }
}

// epilogue: write acc row-major (stride 136) into slab
__device__ __forceinline__ void slab_write_rows(u16* SLAB, int mm, int quad,
        const f32x4* acc, const float* __restrict__ bias) {
    #pragma unroll
    for (int nt = 0; nt < 8; nt++) {
        float b0 = 0, b1 = 0, b2 = 0, b3 = 0;
        if (bias) {
            float4 bb = *(const float4*)(bias + nt * 16 + quad * 4);
            b0 = bb.x; b1 = bb.y; b2 = bb.z; b3 = bb.w;
        }
        *(uint2*)&SLAB[mm * 136 + nt * 16 + quad * 4] =
            pk4(acc[nt][0] + b0, acc[nt][1] + b1, acc[nt][2] + b2, acc[nt][3] + b3);
    }
}
// coalesced flush: per instruction, 4 COMPLETE 256B rows (16 lanes x 16B each)
__device__ __forceinline__ void slab_flush16(const u16* SLAB, int lane, u16* dst) {
    int r4 = lane >> 4, c = lane & 15;
    #pragma unroll
    for (int i = 0; i < 4; i++) {
        int r = i * 4 + r4;
        uint4 v = *(const uint4*)&SLAB[r * 136 + c * 8];
        *(uint4*)(dst + (size_t)r * 128 + c * 8) = v;
    }
}
// same, but non-temporal (bypass L2 allocation) — for write-once streams
__device__ __forceinline__ void slab_flush16_nt(const u16* SLAB, int lane, u16* dst) {
    int r4 = lane >> 4, c = lane & 15;
    #pragma unroll
    for (int i = 0; i < 4; i++) {
        int r = i * 4 + r4;
        u32x4 v = *(const u32x4*)&SLAB[r * 136 + c * 8];
        __builtin_nontemporal_store(v, (u32x4*)(dst + (size_t)r * 128 + c * 8));
    }
}

// ================= sort =================
__global__ __launch_bounds__(256) void k_hist(const int* __restrict__ recv,
                                              u32* __restrict__ cnt) {
    int i = blockIdx.x * 256 + threadIdx.x;
    if (i < N_E) atomicAdd(&cnt[recv[i]], 1u);
}
__global__ __launch_bounds__(256) void k_scan1(u32* __restrict__ data,
                                               u32* __restrict__ bsum) {
    __shared__ u32 s[256];
    int t = threadIdx.x, g = blockIdx.x * 256 + t;
    u32 v = data[g];
    s[t] = v; __syncthreads();
    for (int o = 1; o < 256; o <<= 1) {
        u32 x = (t >= o) ? s[t - o] : 0u;
        __syncthreads(); s[t] += x; __syncthreads();
    }
    data[g] = s[t] - v;
    if (t == 255) bsum[blockIdx.x] = s[255];
}
__global__ __launch_bounds__(256) void k_scan2(u32* __restrict__ bsum) {
    __shared__ u32 s[256];
    int t = threadIdx.x;
    u32 v = bsum[t];
    s[t] = v; __syncthreads();
    for (int o = 1; o < 256; o <<= 1) {
        u32 x = (t >= o) ? s[t - o] : 0u;
        __syncthreads(); s[t] += x; __syncthreads();
    }
    bsum[t] = s[t] - v;
}
__global__ __launch_bounds__(256) void k_scan3(u32* __restrict__ data,
                                               const u32* __restrict__ bsum,
                                               u32* __restrict__ rowptr) {
    int g = blockIdx.x * 256 + threadIdx.x;
    u32 v = data[g] + bsum[blockIdx.x];
    data[g] = v;
    rowptr[g] = v;
    if (g == 0) rowptr[N_P] = N_E;
}
__global__ __launch_bounds__(256) void k_scatter(const int* __restrict__ recv,
                                                 const int* __restrict__ send,
                                                 u32* __restrict__ head,
                                                 u32* __restrict__ perm,
                                                 int* __restrict__ srecv,
                                                 int* __restrict__ ssend) {
    int i = blockIdx.x * 256 + threadIdx.x;
    if (i < N_E) {
        int n = recv[i];
        u32 pos = atomicAdd(&head[n], 1u);
        perm[pos] = (u32)i;
        srecv[pos] = n;
        ssend[pos] = send[i];
    }
}

// ================= weight conversion =================
struct CvtJob { const float* src; u16* dst; int n; int mode; int bstart; };
struct CvtArgs { CvtJob j[15]; };

__global__ __launch_bounds__(256) void k_cvt_all(CvtArgs a) {
    int b = blockIdx.x;
    int ji = 0;
    #pragma unroll
    for (int k = 1; k < 15; k++) if (b >= a.j[k].bstart) ji = k;
    CvtJob jb = a.j[ji];
    int i = (b - jb.bstart) * 256 + threadIdx.x;
    if (i >= jb.n) return;
    if (jb.mode == 0) {
        jb.dst[i] = f2b(jb.src[i]);
    } else if (jb.mode == 2) {
        int r = i >> 7;
        jb.dst[i] = (r < 3) ? f2b(jb.src[i]) : 0;
    } else if (jb.mode == 3) {
        int r = i >> 7, c = i & 127;
        jb.dst[i] = f2b(jb.src[r * 384 + c]);
    } else if (jb.mode == 4) {
        int r = i >> 7, c = i & 127;
        jb.dst[i] = f2b(jb.src[r * 256 + c]);
    } else if (jb.mode == 5) {
        int r = i >> 5, c = i & 31;
        float v = 0.f;
        if (c < 9)       v = jb.src[r * 31 + c];
        else if (c < 15) v = jb.src[r * 31 + 18 + (c - 9)];
        jb.dst[i] = f2b(v);
    } else if (jb.mode == 6) {
        int r = i >> 5, c = i & 31;
        float v = 0.f;
        if (c < 9)       v = jb.src[r * 31 + 9 + c];
        else if (c < 15) v = jb.src[r * 31 + 24 + (c - 9)];
        jb.dst[i] = f2b(v);
    } else if (jb.mode == 7) {
        int r = i >> 5, c = i & 31;
        jb.dst[i] = (c < 15) ? f2b(jb.src[r * 15 + c]) : 0;
    } else {                                  // 8
        jb.dst[i] = f2b(jb.src[i * 31 + 30]);
    }
}

// ================= centroid =================
__global__ __launch_bounds__(256) void k_centroid(const float* __restrict__ state,
                                                  float* __restrict__ cent) {
    int d = blockIdx.x;
    __shared__ float red[256];
    float s = 0.f;
    for (int r = threadIdx.x; r < RIG_; r += 256) s += state[r * 6 + d];
    red[threadIdx.x] = s; __syncthreads();
    for (int o = 128; o > 0; o >>= 1) {
        if (threadIdx.x < o) red[threadIdx.x] += red[threadIdx.x + o];
        __syncthreads();
    }
    if (threadIdx.x == 0) cent[d] = red[0] / (float)RIG_;
}

// ================= particle: feat(15) -> {P(+b0), Q, pe MLP, T} =================
__global__ __launch_bounds__(256, 4) void k_particle_ext(
        const float* __restrict__ state, const float* __restrict__ attr,
        const float* __restrict__ cent,
        const u16* __restrict__ w0r, const u16* __restrict__ w0s,      // [128][32]
        const float* __restrict__ re_b0,
        const u16* __restrict__ pew0, const float* __restrict__ pe_b0, // [128][32]
        const u16* __restrict__ pew1, const float* __restrict__ pe_b1, // [128][128]
        const u16* __restrict__ wp,                                    // [128][128]
        u16* __restrict__ P, u16* __restrict__ Q, u16* __restrict__ T) {
    __shared__ __align__(16) u16 BUF[4 * SLABN];
    int t = threadIdx.x;
    int base = blockIdx.x * 64;
    int wv = t >> 6, lane = t & 63, mm = lane & 15, quad = lane >> 4;
    u16* SLAB = BUF + wv * SLABN;
    size_t wrow = (size_t)(base + wv * 16) * 128;
    // stage features into slab-front f32 scratch (wave-private)
    float* in_s = (float*)SLAB;                  // [16][16] f32 = 1 KB
    for (int it = lane; it < 256; it += 64) {
        int r = it >> 4, c = it & 15;
        if (c < 15) {
            int p = base + wv * 16 + r;
            float v;
            if (c < 3)      v = attr[p * 3 + c];
            else if (c < 9) v = (p < RIG_) ? (state[p * 6 + (c - 3)] - cent[c - 3]) : 0.0f;
            else            v = state[p * 6 + (c - 9)];
            in_s[r * 16 + c] = v;
        }
    }
    // B-frag in registers
    u16 tmp[8];
    #pragma unroll
    for (int j = 0; j < 8; j++) {
        int k = quad * 8 + j;
        tmp[j] = (k < 15) ? f2b(in_s[mm * 16 + k]) : (u16)0;
    }
    bf16x8 xf0 = *(bf16x8*)tmp;
    // P = W0r@feat + re_b0
    {
        f32x4 acc[8] = {};
        #pragma unroll
        for (int nt = 0; nt < 8; nt++) {
            bf16x8 wf = *(const bf16x8*)(w0r + (size_t)(nt * 16 + mm) * 32 + quad * 8);
            acc[nt] = MFMA(wf, xf0, acc[nt]);
        }
        slab_write_rows(SLAB, mm, quad, acc, re_b0);
        slab_flush16(SLAB, lane, P + wrow);
    }
    // Q = W0s@feat
    {
        f32x4 acc[8] = {};
        #pragma unroll
        for (int nt = 0; nt < 8; nt++) {
            bf16x8 wf = *(const bf16x8*)(w0s + (size_t)(nt * 16 + mm) * 32 + quad * 8);
            acc[nt] = MFMA(wf, xf0, acc[nt]);
        }
        slab_write_rows(SLAB, mm, quad, acc, (const float*)0);
        slab_flush16(SLAB, lane, Q + wrow);
    }
    // pe layer1 -> frag layout
    {
        f32x4 acc[8] = {};
        #pragma unroll
        for (int nt = 0; nt < 8; nt++) {
            bf16x8 wf = *(const bf16x8*)(pew0 + (size_t)(nt * 16 + mm) * 32 + quad * 8);
            acc[nt] = MFMA(wf, xf0, acc[nt]);
        }
        #pragma unroll
        for (int nt = 0; nt < 8; nt++) {
            float4 bb = *(const float4*)(pe_b0 + nt * 16 + quad * 4);
            *(uint2*)&SLAB[(((nt * 2 + (quad >> 1)) * 16 + mm) * 8) + (quad & 1) * 4] =
                pk4(fmaxf(acc[nt][0] + bb.x, 0.f), fmaxf(acc[nt][1] + bb.y, 0.f),
                    fmaxf(acc[nt][2] + bb.z, 0.f), fmaxf(acc[nt][3] + bb.w, 0.f));
        }
    }
    layer_inplace(SLAB, mm, quad, pew1, pe_b1);
    // T = Wp@pe
    {
        f32x4 acc[8] = {};
        #pragma unroll
        for (int kc = 0; kc < 4; kc++) {
            bf16x8 xf = *(const bf16x8*)&SLAB[((kc * 4 + quad) * 16 + mm) * 8];
            #pragma unroll
            for (int nt = 0; nt < 8; nt++) {
                bf16x8 wf = *(const bf16x8*)(wp + (size_t)(nt * 16 + mm) * 128 + kc * 32 + quad * 8);
                acc[nt] = MFMA(wf, xf, acc[nt]);
            }
        }
        slab_write_rows(SLAB, mm, quad, acc, (const float*)0);
        slab_flush16(SLAB, lane, T + wrow);
    }
}

// ================= relation: H1 -> L2 -> L3 -> Z (nt stream); barrier-free =================
__global__ __launch_bounds__(256, 8) void k_rel(
        const u16* __restrict__ P, const u16* __restrict__ Q,
        const float* __restrict__ Ra, const u32* __restrict__ perm,
        const int* __restrict__ srecv, const int* __restrict__ ssend,
        const u16* __restrict__ wRab,
        const u16* __restrict__ w1b, const float* __restrict__ b1,
        const u16* __restrict__ w2b, const float* __restrict__ b2,
        const u16* __restrict__ wreb,
        u16* __restrict__ Z) {
    __shared__ __align__(16) u16 BUF[4 * SLABN];   // 17.4 KB
    int t = threadIdx.x;
    long base = (long)blockIdx.x * 64;
    int wv = t >> 6, lane = t & 63, mm = lane & 15, quad = lane >> 4;
    u16* SLAB = BUF + wv * SLABN;
    // stage H1 = relu(P[rv] + Q[sv] + Ra*wRa)   (b0 folded into P)
    {
        int e = wv * 16 + mm;
        int rvp = srecv[base + e];
        int svp = ssend[base + e];
        float ra = Ra[perm[base + e]];
        #pragma unroll
        for (int i = 0; i < 4; i++) {
            int kq = quad + 4 * i;
            uint4 up = *(const uint4*)(P + (size_t)rvp * 128 + kq * 8);
            uint4 uq = *(const uint4*)(Q + (size_t)svp * 128 + kq * 8);
            uint4 uw = *(const uint4*)(wRab + kq * 8);
            const u16* pp = (const u16*)&up; const u16* qq = (const u16*)&uq;
            const u16* ww = (const u16*)&uw;
            u16 ov[8];
            #pragma unroll
            for (int j = 0; j < 8; j++)
                ov[j] = f2b(fmaxf(b2f(pp[j]) + b2f(qq[j]) + ra * b2f(ww[j]), 0.f));
            *(uint4*)&SLAB[(kq * 16 + mm) * 8] = *(uint4*)ov;
        }
    }
    layer_inplace(SLAB, mm, quad, w1b, b1);
    layer_inplace(SLAB, mm, quad, w2b, b2);
    // layer4: Z = Wre @ rel_enc -> row-major slab -> non-temporal full-line stream
    {
        f32x4 acc[8] = {};
        #pragma unroll
        for (int kc = 0; kc < 4; kc++) {
            bf16x8 xf = *(const bf16x8*)&SLAB[((kc * 4 + quad) * 16 + mm) * 8];
            #pragma unroll
            for (int nt = 0; nt < 8; nt++) {
                bf16x8 wf = *(const bf16x8*)(wreb + (size_t)(nt * 16 + mm) * 128 + kc * 32 + quad * 8);
                acc[nt] = MFMA(wf, xf, acc[nt]);
            }
        }
        slab_write_rows(SLAB, mm, quad, acc, (const float*)0);
        slab_flush16_nt(SLAB, lane, Z + (size_t)(base + wv * 16) * 128);
    }
}

// ================= fused propagation step (node-parallel, CSR, no atomics) ======
__global__ __launch_bounds__(256, 8) void k_step(
        const u16* __restrict__ Z, const int* __restrict__ ssend,
        const u32* __restrict__ rowptr,
        const u16* __restrict__ U, const u16* __restrict__ V,
        const float* __restrict__ rpb,
        const u16* __restrict__ T, const u16* __restrict__ wab,
        const float* __restrict__ ppb,
        const u16* __restrict__ wrb, const u16* __restrict__ wsb,
        u16* __restrict__ effb, u16* __restrict__ Uo, u16* __restrict__ Vo,
        int step) {
    __shared__ __align__(16) u16 BUF[4 * SLABN];
    int t = threadIdx.x;
    int wv = t >> 6, lane = t & 63, mm = lane & 15, quad = lane >> 4;
    u16* SLAB = BUF + wv * SLABN;
    int nbase = blockIdx.x * 64 + wv * 16;
    size_t wrow = (size_t)nbase * 128;
    const u32* Z32 = (const u32*)Z;
    const u32* U32 = (const u32*)U;
    const u32* V32 = (const u32*)V;
    float rp0 = rpb[2 * lane], rp1 = rpb[2 * lane + 1];
    // CSR aggregation: wave-private 16 nodes, 2 cols/lane; Z streamed non-temporally
    for (int n = 0; n < 16; n++) {
        int node = nbase + n;
        u32 e0 = rowptr[node], e1 = rowptr[node + 1];
        float s0 = 0.f, s1 = 0.f;
        float u0 = 0.f, u1 = 0.f;
        if (step == 2) {
            u32 uu = U32[(size_t)node * 64 + lane];
            u0 = b2f((u16)uu); u1 = b2f((u16)(uu >> 16));
        }
        for (u32 e = e0; e < e1; e++) {
            u32 z = __builtin_nontemporal_load(&Z32[(size_t)e * 64 + lane]);
            float z0 = b2f((u16)z), z1 = b2f((u16)(z >> 16));
            if (step == 2) {
                int sv = ssend[e];
                u32 vv = V32[(size_t)sv * 64 + lane];
                z0 += u0 + b2f((u16)vv);
                z1 += u1 + b2f((u16)(vv >> 16));
            }
            s0 += fmaxf(z0 + rp0, 0.f);
            s1 += fmaxf(z1 + rp1, 0.f);
        }
        *(u32*)&SLAB[n * 136 + lane * 2] = pk2(s0, s1);   // row-major
    }
    long node = nbase + mm;
    // node GEMM: eff = relu(Wa@s + T + ppb); B-frag read from row-major slab
    uint2 pv[8];
    {
        f32x4 acc[8] = {};
        #pragma unroll
        for (int kc = 0; kc < 4; kc++) {
            bf16x8 xf = *(const bf16x8*)&SLAB[mm * 136 + kc * 32 + quad * 8];
            #pragma unroll
            for (int nt = 0; nt < 8; nt++) {
                bf16x8 wf = *(const bf16x8*)(wab + (size_t)(nt * 16 + mm) * 128 + kc * 32 + quad * 8);
                acc[nt] = MFMA(wf, xf, acc[nt]);
            }
        }
        #pragma unroll
        for (int nt = 0; nt < 8; nt++) {
            int col0 = nt * 16 + quad * 4;
            float4 bb = *(const float4*)(ppb + col0);
            uint2 tv = *(const uint2*)(T + node * 128 + col0);
            const u16* tt = (const u16*)&tv;
            pv[nt] = pk4(fmaxf(acc[nt][0] + b2f(tt[0]) + bb.x, 0.f),
                         fmaxf(acc[nt][1] + b2f(tt[1]) + bb.y, 0.f),
                         fmaxf(acc[nt][2] + b2f(tt[2]) + bb.z, 0.f),
                         fmaxf(acc[nt][3] + b2f(tt[3]) + bb.w, 0.f));
        }
    }
    if (step != 1) {
        #pragma unroll
        for (int nt = 0; nt < 8; nt++)
            *(uint2*)&SLAB[mm * 136 + nt * 16 + quad * 4] = pv[nt];
        slab_flush16(SLAB, lane, effb + wrow);
        return;
    }
    // step 1: frag-write eff, U/V GEMMs, then flush effb/U/V coalesced
    #pragma unroll
    for (int nt = 0; nt < 8; nt++)
        *(uint2*)&SLAB[(((nt * 2 + (quad >> 1)) * 16 + mm) * 8) + (quad & 1) * 4] = pv[nt];
    f32x4 ua[8] = {}, va[8] = {};
    #pragma unroll
    for (int kc = 0; kc < 4; kc++) {
        bf16x8 xf = *(const bf16x8*)&SLAB[((kc * 4 + quad) * 16 + mm) * 8];
        #pragma unroll
        for (int nt = 0; nt < 8; nt++) {
            bf16x8 wu = *(const bf16x8*)(wrb + (size_t)(nt * 16 + mm) * 128 + kc * 32 + quad * 8);
            bf16x8 wvv = *(const bf16x8*)(wsb + (size_t)(nt * 16 + mm) * 128 + kc * 32 + quad * 8);
            ua[nt] = MFMA(wu, xf, ua[nt]);
            va[nt] = MFMA(wvv, xf, va[nt]);
        }
    }
    #pragma unroll
    for (int nt = 0; nt < 8; nt++)
        *(uint2*)&SLAB[mm * 136 + nt * 16 + quad * 4] = pv[nt];
    slab_flush16(SLAB, lane, effb + wrow);
    slab_write_rows(SLAB, mm, quad, ua, (const float*)0);
    slab_flush16(SLAB, lane, Uo + wrow);
    slab_write_rows(SLAB, mm, quad, va, (const float*)0);
    slab_flush16(SLAB, lane, Vo + wrow);
}

// ================= pooled mean =================
__global__ __launch_bounds__(256) void k_pool(const u16* __restrict__ effb,
                                              float* __restrict__ pooled) {
    int f = blockIdx.x;
    __shared__ float red[256];
    float s = 0.f;
    for (int r = threadIdx.x; r < RIG_; r += 256) s += b2f(effb[(size_t)r * 128 + f]);
    red[threadIdx.x] = s; __syncthreads();
    for (int o = 128; o > 0; o >>= 1) {
        if (threadIdx.x < o) red[threadIdx.x] += red[threadIdx.x + o];
        __syncthreads();
    }
    if (threadIdx.x == 0) pooled[f] = red[0] / (float)RIG_;
}

// ================= rigid head =================
__global__ __launch_bounds__(128) void k_rigid_head(
        const float* __restrict__ pooled,
        const float* __restrict__ w0, const float* __restrict__ b0,
        const float* __restrict__ w1, const float* __restrict__ b1,
        const float* __restrict__ w2, const float* __restrict__ b2,
        float* __restrict__ rig) {
    __shared__ float pl[128], ha[128], hb[128], tv[7];
    int t = threadIdx.x;
    pl[t] = pooled[t];
    __syncthreads();
    float a = b0[t];
    for (int k = 0; k < 128; k++) a += w0[t * 128 + k] * pl[k];
    ha[t] = fmaxf(a, 0.f);
    __syncthreads();
    a = b1[t];
    for (int k = 0; k < 128; k++) a += w1[t * 128 + k] * ha[k];
    hb[t] = fmaxf(a, 0.f);
    __syncthreads();
    if (t < 7) {
        float s = b2[t];
        for (int k = 0; k < 128; k++) s += w2[t * 128 + k] * hb[k];
        tv[t] = s;
    }
    __syncthreads();
    if (t == 0) {
        float w = tv[0], x = tv[1], y = tv[2], z = tv[3];
        float n = sqrtf(w * w + x * x + y * y + z * z);
        w /= n; x /= n; y /= n; z /= n;
        rig[0] = 1.f - 2.f * (y * y + z * z); rig[1] = 2.f * (x * y + z * w); rig[2] = 2.f * (x * z - y * w);
        rig[3] = 2.f * (x * y - z * w); rig[4] = 1.f - 2.f * (x * x + z * z); rig[5] = 2.f * (y * z + x * w);
        rig[6] = 2.f * (x * z + y * w); rig[7] = 2.f * (y * z - x * w); rig[8] = 1.f - 2.f * (x * x + y * y);
        rig[9] = tv[4]; rig[10] = tv[5]; rig[11] = tv[6];
    }
}

// ================= rigid output =================
__global__ __launch_bounds__(256) void k_rigid_out(
        const float* __restrict__ state, const float* __restrict__ cent,
        const float* __restrict__ rig, float* __restrict__ out) {
    int i = blockIdx.x * 256 + threadIdx.x;
    if (i >= RIG_) return;
    float p0[3], d[3];
    #pragma unroll
    for (int k = 0; k < 3; k++) { p0[k] = state[i * 6 + k]; d[k] = p0[k] - cent[k]; }
    #pragma unroll
    for (int j = 0; j < 3; j++) {
        float p1 = rig[0 * 3 + j] * d[0] + rig[1 * 3 + j] * d[1] + rig[2 * 3 + j] * d[2]
                 + rig[9 + j] + cent[j];
        out[i * 3 + j] = (p1 - p0[j]) * 60.0f;
    }
}

// ================= fluid: 128 -> 128 -> 128 -> 3 =================
__global__ __launch_bounds__(256, 8) void k_fluid(
        const u16* __restrict__ effb,
        const u16* __restrict__ w0b, const float* __restrict__ b0,
        const u16* __restrict__ w1b, const float* __restrict__ b1,
        const u16* __restrict__ w2b, const float* __restrict__ b2,
        float* __restrict__ out) {
    __shared__ __align__(16) u16 BUF[4 * SLABN];
    int t = threadIdx.x;
    long base = RIG_ + (long)blockIdx.x * 64;
    int wv = t >> 6, lane = t & 63, mm = lane & 15, quad = lane >> 4;
    u16* SLAB = BUF + wv * SLABN;
    long node = base + wv * 16 + mm;
    #pragma unroll
    for (int i = 0; i < 4; i++) {
        int kq = quad + 4 * i;
        *(uint4*)&SLAB[(kq * 16 + mm) * 8] =
            *(const uint4*)(effb + node * 128 + kq * 8);
    }
    layer_inplace(SLAB, mm, quad, w0b, b0);
    layer_inplace(SLAB, mm, quad, w1b, b1);
    {
        f32x4 acc = {};
        #pragma unroll
        for (int kc = 0; kc < 4; kc++) {
            bf16x8 xf = *(const bf16x8*)&SLAB[((kc * 4 + quad) * 16 + mm) * 8];
            bf16x8 wf = *(const bf16x8*)(w2b + (size_t)mm * 128 + kc * 32 + quad * 8);
            acc = MFMA(wf, xf, acc);
        }
        if (quad == 0) {
            #pragma unroll
            for (int rg = 0; rg < 3; rg++)
                out[node * 3 + rg] = acc[rg] + b2[rg];
        }
    }
}

// ================= host =================
extern "C" void kernel_launch(void* const* d_in, const int* in_sizes, int n_in,
                              void* d_out, int out_size, void* d_ws, size_t ws_size,
                              hipStream_t stream) {
    const float* state = (const float*)d_in[0];
    const float* attr  = (const float*)d_in[1];
    const float* Ra    = (const float*)d_in[2];
    const int*   recv  = (const int*)d_in[3];
    const int*   send  = (const int*)d_in[4];
    const float* pe_w0 = (const float*)d_in[5];  const float* pe_b0 = (const float*)d_in[6];
    const float* pe_w1 = (const float*)d_in[7];  const float* pe_b1 = (const float*)d_in[8];
    const float* re_w0 = (const float*)d_in[9];  const float* re_b0 = (const float*)d_in[10];
    const float* re_w1 = (const float*)d_in[11]; const float* re_b1 = (const float*)d_in[12];
    const float* re_w2 = (const float*)d_in[13]; const float* re_b2 = (const float*)d_in[14];
    const float* rp_w  = (const float*)d_in[15]; const float* rp_b  = (const float*)d_in[16];
    const float* pp_w  = (const float*)d_in[17]; const float* pp_b  = (const float*)d_in[18];
    const float* rg_w0 = (const float*)d_in[19]; const float* rg_b0 = (const float*)d_in[20];
    const float* rg_w1 = (const float*)d_in[21]; const float* rg_b1 = (const float*)d_in[22];
    const float* rg_w2 = (const float*)d_in[23]; const float* rg_b2 = (const float*)d_in[24];
    const float* fl_w0 = (const float*)d_in[25]; const float* fl_b0 = (const float*)d_in[26];
    const float* fl_w1 = (const float*)d_in[27]; const float* fl_b1 = (const float*)d_in[28];
    const float* fl_w2 = (const float*)d_in[29]; const float* fl_b2 = (const float*)d_in[30];
    float* out = (float*)d_out;

    char* p = (char*)d_ws;
    auto alloc = [&](size_t bytes) { char* r = p; p += (bytes + 255) / 256 * 256; return r; };
    float* cent    = (float*)alloc(8 * 4);
    float* pooled  = (float*)alloc(128 * 4);
    float* rig     = (float*)alloc(16 * 4);
    u32*   rowhead = (u32*)alloc((size_t)N_P * 4);
    u32*   rowptr  = (u32*)alloc(((size_t)N_P + 1) * 4);
    u32*   bsum    = (u32*)alloc(256 * 4);
    u32*   perm    = (u32*)alloc((size_t)N_E * 4);
    int*   srecv   = (int*)alloc((size_t)N_E * 4);
    int*   ssend   = (int*)alloc((size_t)N_E * 4);
    u16*   Z       = (u16*)alloc((size_t)N_E * 128 * 2);
    u16*   effb    = (u16*)alloc((size_t)N_P * 128 * 2);
    u16*   T       = (u16*)alloc((size_t)N_P * 128 * 2);
    u16*   P       = (u16*)alloc((size_t)N_P * 128 * 2);   // aliased as U after k_rel
    u16*   Q       = (u16*)alloc((size_t)N_P * 128 * 2);   // aliased as V after k_rel
    u16*   wreb    = (u16*)alloc(128 * 128 * 2);
    u16*   wrb     = (u16*)alloc(128 * 128 * 2);
    u16*   wsb     = (u16*)alloc(128 * 128 * 2);
    u16*   wpb     = (u16*)alloc(128 * 128 * 2);
    u16*   wab     = (u16*)alloc(128 * 128 * 2);
    u16*   rw1b    = (u16*)alloc(128 * 128 * 2);
    u16*   rw2b    = (u16*)alloc(128 * 128 * 2);
    u16*   pew1b   = (u16*)alloc(128 * 128 * 2);
    u16*   flw0b   = (u16*)alloc(128 * 128 * 2);
    u16*   flw1b   = (u16*)alloc(128 * 128 * 2);
    u16*   flw2b   = (u16*)alloc(16 * 128 * 2);
    u16*   w0rb    = (u16*)alloc(128 * 32 * 2);
    u16*   w0sb    = (u16*)alloc(128 * 32 * 2);
    u16*   pew0b   = (u16*)alloc(128 * 32 * 2);
    u16*   wRab    = (u16*)alloc(128 * 2);
    size_t need = (size_t)(p - (char*)d_ws);
    if (ws_size < need) {
        fprintf(stderr, "kernel_launch: ws_size %zu < needed %zu\n", ws_size, need);
        return;
    }
    u16* U = P; u16* V = Q;

    // sort edges by recv (also builds CSR rowptr)
    hipMemsetAsync(rowhead, 0, (size_t)N_P * 4, stream);
    k_hist<<<N_E / 256, 256, 0, stream>>>(recv, rowhead);
    k_scan1<<<N_P / 256, 256, 0, stream>>>(rowhead, bsum);
    k_scan2<<<1, 256, 0, stream>>>(bsum);
    k_scan3<<<N_P / 256, 256, 0, stream>>>(rowhead, bsum, rowptr);
    k_scatter<<<N_E / 256, 256, 0, stream>>>(recv, send, rowhead, perm, srecv, ssend);

    // weight conversion
    CvtArgs ca;
    int bs = 0;
    auto addjob = [&](int idx, const float* s, u16* d, int n, int mode) {
        ca.j[idx] = {s, d, n, mode, bs};
        bs += (n + 255) / 256;
    };
    addjob(0,  rp_w,        wreb,  128 * 128, 3);
    addjob(1,  rp_w + 128,  wrb,   128 * 128, 3);
    addjob(2,  rp_w + 256,  wsb,   128 * 128, 3);
    addjob(3,  pp_w,        wpb,   128 * 128, 4);
    addjob(4,  pp_w + 128,  wab,   128 * 128, 4);
    addjob(5,  re_w1,       rw1b,  128 * 128, 0);
    addjob(6,  re_w2,       rw2b,  128 * 128, 0);
    addjob(7,  pe_w1,       pew1b, 128 * 128, 0);
    addjob(8,  fl_w0,       flw0b, 128 * 128, 0);
    addjob(9,  fl_w1,       flw1b, 128 * 128, 0);
    addjob(10, fl_w2,       flw2b, 16 * 128,  2);
    addjob(11, re_w0,       w0rb,  128 * 32,  5);
    addjob(12, re_w0,       w0sb,  128 * 32,  6);
    addjob(13, pe_w0,       pew0b, 128 * 32,  7);
    addjob(14, re_w0,       wRab,  128,       8);
    k_cvt_all<<<bs, 256, 0, stream>>>(ca);

    // encoders
    k_centroid<<<6, 256, 0, stream>>>(state, cent);
    k_particle_ext<<<N_P / 64, 256, 0, stream>>>(state, attr, cent,
                                                 w0rb, w0sb, re_b0, pew0b, pe_b0,
                                                 pew1b, pe_b1, wpb, P, Q, T);

    // relation encoder -> Z
    k_rel<<<N_E / 64, 256, 0, stream>>>(P, Q, Ra, perm, srecv, ssend, wRab,
                                        rw1b, re_b1, rw2b, re_b2, wreb, Z);

    // propagation steps (node-parallel CSR, no atomics)
    k_step<<<N_P / 64, 256, 0, stream>>>(Z, ssend, rowptr, U, V, rp_b,
                                         T, wab, pp_b, wrb, wsb, effb, U, V, 1);
    k_step<<<N_P / 64, 256, 0, stream>>>(Z, ssend, rowptr, U, V, rp_b,
                                         T, wab, pp_b, wrb, wsb, effb, U, V, 2);

    // heads
    k_pool<<<128, 256, 0, stream>>>(effb, pooled);
    k_rigid_head<<<1, 128, 0, stream>>>(pooled, rg_w0, rg_b0, rg_w1, rg_b1, rg_w2, rg_b2, rig);
    k_rigid_out<<<(RIG_ + 255) / 256, 256, 0, stream>>>(state, cent, rig, out);
    k_fluid<<<(N_P - RIG_) / 64, 256, 0, stream>>>(effb, flw0b, fl_b0, flw1b, fl_b1,
                                                   flw2b, fl_b2, out);
}

// Round 10
// 961.291 us; speedup vs baseline: 1.2449x; 1.2449x over previous
//
#include <hip/hip_runtime.h>
#include <hip/hip_bf16.h>
#include <cstdio>

#define N_P   65536
#define N_E   524288
#define RIG_  4096

typedef __attribute__((ext_vector_type(8))) short bf16x8;
typedef __attribute__((ext_vector_type(4))) float f32x4;
typedef unsigned short u16;
typedef unsigned int   u32;

#define SLABN 2176            // 16 rows * 136 u16 per wave slab

__device__ __forceinline__ u16 f2b(float x) {
    __hip_bfloat16 h = __float2bfloat16(x);
    return *(u16*)&h;
}
__device__ __forceinline__ float b2f(u16 u) {
    union { unsigned u; float f; } c; c.u = ((unsigned)u) << 16; return c.f;
}
__device__ __forceinline__ unsigned pk2(float x, float y) {
    return (unsigned)f2b(x) | ((unsigned)f2b(y) << 16);
}
__device__ __forceinline__ uint2 pk4(float a, float b, float c, float d) {
    uint2 r; r.x = pk2(a, b); r.y = pk2(c, d); return r;
}
#define MFMA(a,b,c) __builtin_amdgcn_mfma_f32_16x16x32_bf16((a),(b),(c),0,0,0)

// K=128 layer, in-place on a wave-private slab (frag layout), weights as A-operand.
__device__ __forceinline__ void layer_inplace(u16* SLAB, int mm, int quad,
        const u16* __restrict__ wb, const float* __restrict__ bias) {
    f32x4 acc[8] = {};
    #pragma unroll
    for (int kc = 0; kc < 4; kc++) {
        bf16x8 xf = *(const bf16x8*)&SLAB[((kc * 4 + quad) * 16 + mm) * 8];
        #pragma unroll
        for (int nt = 0; nt < 8; nt++) {
            bf16x8 wf = *(const bf16x8*)(wb + (size_t)(nt * 16 + mm) * 128 + kc * 32 + quad * 8);
            acc[nt] = MFMA(wf, xf, acc[nt]);
        }
    }
    #pragma unroll
    for (int nt = 0; nt < 8; nt++) {
        float4 bb = *(const float4*)(bias + nt * 16 + quad * 4);
        *(uint2*)&SLAB[(((nt * 2 + (quad >> 1)) * 16 + mm) * 8) + (quad & 1) * 4] =
            pk4(fmaxf(acc[nt][0] + bb.x, 0.f), fmaxf(acc[nt][1] + bb.y, 0.f),
                fmaxf(acc[nt][2] + bb.z, 0.f), fmaxf(acc[nt][3] + bb.w, 0.f));
    }
}

// epilogue: write acc row-major (stride 136) into slab
__device__ __forceinline__ void slab_write_rows(u16* SLAB, int mm, int quad,
        const f32x4* acc, const float* __restrict__ bias) {
    #pragma unroll
    for (int nt = 0; nt < 8; nt++) {
        float b0 = 0, b1 = 0, b2 = 0, b3 = 0;
        if (bias) {
            float4 bb = *(const float4*)(bias + nt * 16 + quad * 4);
            b0 = bb.x; b1 = bb.y; b2 = bb.z; b3 = bb.w;
        }
        *(uint2*)&SLAB[mm * 136 + nt * 16 + quad * 4] =
            pk4(acc[nt][0] + b0, acc[nt][1] + b1, acc[nt][2] + b2, acc[nt][3] + b3);
    }
}
// coalesced flush: per instruction, 4 COMPLETE 256B rows (16 lanes x 16B each)
__device__ __forceinline__ void slab_flush16(const u16* SLAB, int lane, u16* dst) {
    int r4 = lane >> 4, c = lane & 15;
    #pragma unroll
    for (int i = 0; i < 4; i++) {
        int r = i * 4 + r4;
        uint4 v = *(const uint4*)&SLAB[r * 136 + c * 8];
        *(uint4*)(dst + (size_t)r * 128 + c * 8) = v;
    }
}

// ================= sort =================
__global__ __launch_bounds__(256) void k_hist(const int* __restrict__ recv,
                                              u32* __restrict__ cnt) {
    int i = blockIdx.x * 256 + threadIdx.x;
    if (i < N_E) atomicAdd(&cnt[recv[i]], 1u);
}
__global__ __launch_bounds__(256) void k_scan1(u32* __restrict__ data,
                                               u32* __restrict__ bsum) {
    __shared__ u32 s[256];
    int t = threadIdx.x, g = blockIdx.x * 256 + t;
    u32 v = data[g];
    s[t] = v; __syncthreads();
    for (int o = 1; o < 256; o <<= 1) {
        u32 x = (t >= o) ? s[t - o] : 0u;
        __syncthreads(); s[t] += x; __syncthreads();
    }
    data[g] = s[t] - v;
    if (t == 255) bsum[blockIdx.x] = s[255];
}
__global__ __launch_bounds__(256) void k_scan2(u32* __restrict__ bsum) {
    __shared__ u32 s[256];
    int t = threadIdx.x;
    u32 v = bsum[t];
    s[t] = v; __syncthreads();
    for (int o = 1; o < 256; o <<= 1) {
        u32 x = (t >= o) ? s[t - o] : 0u;
        __syncthreads(); s[t] += x; __syncthreads();
    }
    bsum[t] = s[t] - v;
}
__global__ __launch_bounds__(256) void k_scan3(u32* __restrict__ data,
                                               const u32* __restrict__ bsum,
                                               u32* __restrict__ rowptr) {
    int g = blockIdx.x * 256 + threadIdx.x;
    u32 v = data[g] + bsum[blockIdx.x];
    data[g] = v;
    rowptr[g] = v;
    if (g == 0) rowptr[N_P] = N_E;
}
__global__ __launch_bounds__(256) void k_scatter(const int* __restrict__ recv,
                                                 const int* __restrict__ send,
                                                 const float* __restrict__ Ra,
                                                 u32* __restrict__ head,
                                                 int* __restrict__ srecv,
                                                 int* __restrict__ ssend,
                                                 float* __restrict__ sra) {
    int i = blockIdx.x * 256 + threadIdx.x;
    if (i < N_E) {
        int n = recv[i];
        u32 pos = atomicAdd(&head[n], 1u);
        srecv[pos] = n;
        ssend[pos] = send[i];
        sra[pos]   = Ra[i];
    }
}

// ================= weight conversion =================
struct CvtJob { const float* src; u16* dst; int n; int mode; int bstart; };
struct CvtArgs { CvtJob j[15]; };

__global__ __launch_bounds__(256) void k_cvt_all(CvtArgs a) {
    int b = blockIdx.x;
    int ji = 0;
    #pragma unroll
    for (int k = 1; k < 15; k++) if (b >= a.j[k].bstart) ji = k;
    CvtJob jb = a.j[ji];
    int i = (b - jb.bstart) * 256 + threadIdx.x;
    if (i >= jb.n) return;
    if (jb.mode == 0) {
        jb.dst[i] = f2b(jb.src[i]);
    } else if (jb.mode == 2) {
        int r = i >> 7;
        jb.dst[i] = (r < 3) ? f2b(jb.src[i]) : 0;
    } else if (jb.mode == 3) {
        int r = i >> 7, c = i & 127;
        jb.dst[i] = f2b(jb.src[r * 384 + c]);
    } else if (jb.mode == 4) {
        int r = i >> 7, c = i & 127;
        jb.dst[i] = f2b(jb.src[r * 256 + c]);
    } else if (jb.mode == 5) {
        int r = i >> 5, c = i & 31;
        float v = 0.f;
        if (c < 9)       v = jb.src[r * 31 + c];
        else if (c < 15) v = jb.src[r * 31 + 18 + (c - 9)];
        jb.dst[i] = f2b(v);
    } else if (jb.mode == 6) {
        int r = i >> 5, c = i & 31;
        float v = 0.f;
        if (c < 9)       v = jb.src[r * 31 + 9 + c];
        else if (c < 15) v = jb.src[r * 31 + 24 + (c - 9)];
        jb.dst[i] = f2b(v);
    } else if (jb.mode == 7) {
        int r = i >> 5, c = i & 31;
        jb.dst[i] = (c < 15) ? f2b(jb.src[r * 15 + c]) : 0;
    } else {                                  // 8
        jb.dst[i] = f2b(jb.src[i * 31 + 30]);
    }
}

// ================= centroid =================
__global__ __launch_bounds__(256) void k_centroid(const float* __restrict__ state,
                                                  float* __restrict__ cent) {
    int d = blockIdx.x;
    __shared__ float red[256];
    float s = 0.f;
    for (int r = threadIdx.x; r < RIG_; r += 256) s += state[r * 6 + d];
    red[threadIdx.x] = s; __syncthreads();
    for (int o = 128; o > 0; o >>= 1) {
        if (threadIdx.x < o) red[threadIdx.x] += red[threadIdx.x + o];
        __syncthreads();
    }
    if (threadIdx.x == 0) cent[d] = red[0] / (float)RIG_;
}

// ================= particle: feat(15) -> {P(+b0), Q, pe MLP, T} =================
__global__ __launch_bounds__(256, 4) void k_particle_ext(
        const float* __restrict__ state, const float* __restrict__ attr,
        const float* __restrict__ cent,
        const u16* __restrict__ w0r, const u16* __restrict__ w0s,      // [128][32]
        const float* __restrict__ re_b0,
        const u16* __restrict__ pew0, const float* __restrict__ pe_b0, // [128][32]
        const u16* __restrict__ pew1, const float* __restrict__ pe_b1, // [128][128]
        const u16* __restrict__ wp,                                    // [128][128]
        u16* __restrict__ P, u16* __restrict__ Q, u16* __restrict__ T) {
    __shared__ __align__(16) u16 BUF[4 * SLABN];
    int t = threadIdx.x;
    int base = blockIdx.x * 64;
    int wv = t >> 6, lane = t & 63, mm = lane & 15, quad = lane >> 4;
    u16* SLAB = BUF + wv * SLABN;
    size_t wrow = (size_t)(base + wv * 16) * 128;
    // stage features into slab-front f32 scratch (wave-private)
    float* in_s = (float*)SLAB;                  // [16][16] f32 = 1 KB
    for (int it = lane; it < 256; it += 64) {
        int r = it >> 4, c = it & 15;
        if (c < 15) {
            int p = base + wv * 16 + r;
            float v;
            if (c < 3)      v = attr[p * 3 + c];
            else if (c < 9) v = (p < RIG_) ? (state[p * 6 + (c - 3)] - cent[c - 3]) : 0.0f;
            else            v = state[p * 6 + (c - 9)];
            in_s[r * 16 + c] = v;
        }
    }
    // B-frag in registers
    u16 tmp[8];
    #pragma unroll
    for (int j = 0; j < 8; j++) {
        int k = quad * 8 + j;
        tmp[j] = (k < 15) ? f2b(in_s[mm * 16 + k]) : (u16)0;
    }
    bf16x8 xf0 = *(bf16x8*)tmp;
    // P = W0r@feat + re_b0
    {
        f32x4 acc[8] = {};
        #pragma unroll
        for (int nt = 0; nt < 8; nt++) {
            bf16x8 wf = *(const bf16x8*)(w0r + (size_t)(nt * 16 + mm) * 32 + quad * 8);
            acc[nt] = MFMA(wf, xf0, acc[nt]);
        }
        slab_write_rows(SLAB, mm, quad, acc, re_b0);
        slab_flush16(SLAB, lane, P + wrow);
    }
    // Q = W0s@feat
    {
        f32x4 acc[8] = {};
        #pragma unroll
        for (int nt = 0; nt < 8; nt++) {
            bf16x8 wf = *(const bf16x8*)(w0s + (size_t)(nt * 16 + mm) * 32 + quad * 8);
            acc[nt] = MFMA(wf, xf0, acc[nt]);
        }
        slab_write_rows(SLAB, mm, quad, acc, (const float*)0);
        slab_flush16(SLAB, lane, Q + wrow);
    }
    // pe layer1 -> frag layout
    {
        f32x4 acc[8] = {};
        #pragma unroll
        for (int nt = 0; nt < 8; nt++) {
            bf16x8 wf = *(const bf16x8*)(pew0 + (size_t)(nt * 16 + mm) * 32 + quad * 8);
            acc[nt] = MFMA(wf, xf0, acc[nt]);
        }
        #pragma unroll
        for (int nt = 0; nt < 8; nt++) {
            float4 bb = *(const float4*)(pe_b0 + nt * 16 + quad * 4);
            *(uint2*)&SLAB[(((nt * 2 + (quad >> 1)) * 16 + mm) * 8) + (quad & 1) * 4] =
                pk4(fmaxf(acc[nt][0] + bb.x, 0.f), fmaxf(acc[nt][1] + bb.y, 0.f),
                    fmaxf(acc[nt][2] + bb.z, 0.f), fmaxf(acc[nt][3] + bb.w, 0.f));
        }
    }
    layer_inplace(SLAB, mm, quad, pew1, pe_b1);
    // T = Wp@pe
    {
        f32x4 acc[8] = {};
        #pragma unroll
        for (int kc = 0; kc < 4; kc++) {
            bf16x8 xf = *(const bf16x8*)&SLAB[((kc * 4 + quad) * 16 + mm) * 8];
            #pragma unroll
            for (int nt = 0; nt < 8; nt++) {
                bf16x8 wf = *(const bf16x8*)(wp + (size_t)(nt * 16 + mm) * 128 + kc * 32 + quad * 8);
                acc[nt] = MFMA(wf, xf, acc[nt]);
            }
        }
        slab_write_rows(SLAB, mm, quad, acc, (const float*)0);
        slab_flush16(SLAB, lane, T + wrow);
    }
}

// ================= relation: H1 -> L2 -> L3 -> Z; 4 blocks/CU (store-coalescer limit) =====
__global__ __launch_bounds__(256, 4) void k_rel(
        const u16* __restrict__ P, const u16* __restrict__ Q,
        const float* __restrict__ sra,
        const int* __restrict__ srecv, const int* __restrict__ ssend,
        const u16* __restrict__ wRab,
        const u16* __restrict__ w1b, const float* __restrict__ b1,
        const u16* __restrict__ w2b, const float* __restrict__ b2,
        const u16* __restrict__ wreb,
        u16* __restrict__ Z) {
    __shared__ __align__(16) u16 BUF[4 * SLABN];   // 17.4 KB
    int t = threadIdx.x;
    long base = (long)blockIdx.x * 64;
    int wv = t >> 6, lane = t & 63, mm = lane & 15, quad = lane >> 4;
    u16* SLAB = BUF + wv * SLABN;
    // stage H1 = relu(P[rv] + Q[sv] + Ra*wRa)   (b0 folded into P)
    {
        int e = wv * 16 + mm;
        int rvp = srecv[base + e];
        int svp = ssend[base + e];
        float ra = sra[base + e];
        #pragma unroll
        for (int i = 0; i < 4; i++) {
            int kq = quad + 4 * i;
            uint4 up = *(const uint4*)(P + (size_t)rvp * 128 + kq * 8);
            uint4 uq = *(const uint4*)(Q + (size_t)svp * 128 + kq * 8);
            uint4 uw = *(const uint4*)(wRab + kq * 8);
            const u16* pp = (const u16*)&up; const u16* qq = (const u16*)&uq;
            const u16* ww = (const u16*)&uw;
            u16 ov[8];
            #pragma unroll
            for (int j = 0; j < 8; j++)
                ov[j] = f2b(fmaxf(b2f(pp[j]) + b2f(qq[j]) + ra * b2f(ww[j]), 0.f));
            *(uint4*)&SLAB[(kq * 16 + mm) * 8] = *(uint4*)ov;
        }
    }
    layer_inplace(SLAB, mm, quad, w1b, b1);
    layer_inplace(SLAB, mm, quad, w2b, b2);
    // layer4: Z = Wre @ rel_enc -> row-major slab -> coalesced full-line store
    {
        f32x4 acc[8] = {};
        #pragma unroll
        for (int kc = 0; kc < 4; kc++) {
            bf16x8 xf = *(const bf16x8*)&SLAB[((kc * 4 + quad) * 16 + mm) * 8];
            #pragma unroll
            for (int nt = 0; nt < 8; nt++) {
                bf16x8 wf = *(const bf16x8*)(wreb + (size_t)(nt * 16 + mm) * 128 + kc * 32 + quad * 8);
                acc[nt] = MFMA(wf, xf, acc[nt]);
            }
        }
        slab_write_rows(SLAB, mm, quad, acc, (const float*)0);
        slab_flush16(SLAB, lane, Z + (size_t)(base + wv * 16) * 128);
    }
}

// ================= fused propagation step (node-parallel, CSR, no atomics) ======
__global__ __launch_bounds__(256, 4) void k_step(
        const u16* __restrict__ Z, const int* __restrict__ ssend,
        const u32* __restrict__ rowptr,
        const u16* __restrict__ U, const u16* __restrict__ V,
        const float* __restrict__ rpb,
        const u16* __restrict__ T, const u16* __restrict__ wab,
        const float* __restrict__ ppb,
        const u16* __restrict__ wrb, const u16* __restrict__ wsb,
        u16* __restrict__ effb, u16* __restrict__ Uo, u16* __restrict__ Vo,
        int step) {
    __shared__ __align__(16) u16 BUF[4 * SLABN];
    int t = threadIdx.x;
    int wv = t >> 6, lane = t & 63, mm = lane & 15, quad = lane >> 4;
    u16* SLAB = BUF + wv * SLABN;
    int nbase = blockIdx.x * 64 + wv * 16;
    size_t wrow = (size_t)nbase * 128;
    const u32* Z32 = (const u32*)Z;
    const u32* U32 = (const u32*)U;
    const u32* V32 = (const u32*)V;
    float rp0 = rpb[2 * lane], rp1 = rpb[2 * lane + 1];
    // CSR aggregation: wave-private 16 nodes, 2 cols/lane; Z streamed non-temporally
    for (int n = 0; n < 16; n++) {
        int node = nbase + n;
        u32 e0 = rowptr[node], e1 = rowptr[node + 1];
        float s0 = 0.f, s1 = 0.f;
        float u0 = 0.f, u1 = 0.f;
        if (step == 2) {
            u32 uu = U32[(size_t)node * 64 + lane];
            u0 = b2f((u16)uu); u1 = b2f((u16)(uu >> 16));
        }
        for (u32 e = e0; e < e1; e++) {
            u32 z = __builtin_nontemporal_load(&Z32[(size_t)e * 64 + lane]);
            float z0 = b2f((u16)z), z1 = b2f((u16)(z >> 16));
            if (step == 2) {
                int sv = ssend[e];
                u32 vv = V32[(size_t)sv * 64 + lane];
                z0 += u0 + b2f((u16)vv);
                z1 += u1 + b2f((u16)(vv >> 16));
            }
            s0 += fmaxf(z0 + rp0, 0.f);
            s1 += fmaxf(z1 + rp1, 0.f);
        }
        *(u32*)&SLAB[n * 136 + lane * 2] = pk2(s0, s1);   // row-major
    }
    long node = nbase + mm;
    // node GEMM: eff = relu(Wa@s + T + ppb); B-frag read from row-major slab
    uint2 pv[8];
    {
        f32x4 acc[8] = {};
        #pragma unroll
        for (int kc = 0; kc < 4; kc++) {
            bf16x8 xf = *(const bf16x8*)&SLAB[mm * 136 + kc * 32 + quad * 8];
            #pragma unroll
            for (int nt = 0; nt < 8; nt++) {
                bf16x8 wf = *(const bf16x8*)(wab + (size_t)(nt * 16 + mm) * 128 + kc * 32 + quad * 8);
                acc[nt] = MFMA(wf, xf, acc[nt]);
            }
        }
        #pragma unroll
        for (int nt = 0; nt < 8; nt++) {
            int col0 = nt * 16 + quad * 4;
            float4 bb = *(const float4*)(ppb + col0);
            uint2 tv = *(const uint2*)(T + node * 128 + col0);
            const u16* tt = (const u16*)&tv;
            pv[nt] = pk4(fmaxf(acc[nt][0] + b2f(tt[0]) + bb.x, 0.f),
                         fmaxf(acc[nt][1] + b2f(tt[1]) + bb.y, 0.f),
                         fmaxf(acc[nt][2] + b2f(tt[2]) + bb.z, 0.f),
                         fmaxf(acc[nt][3] + b2f(tt[3]) + bb.w, 0.f));
        }
    }
    if (step != 1) {
        #pragma unroll
        for (int nt = 0; nt < 8; nt++)
            *(uint2*)&SLAB[mm * 136 + nt * 16 + quad * 4] = pv[nt];
        slab_flush16(SLAB, lane, effb + wrow);
        return;
    }
    // step 1: frag-write eff, U/V GEMMs, then flush effb/U/V coalesced
    #pragma unroll
    for (int nt = 0; nt < 8; nt++)
        *(uint2*)&SLAB[(((nt * 2 + (quad >> 1)) * 16 + mm) * 8) + (quad & 1) * 4] = pv[nt];
    f32x4 ua[8] = {}, va[8] = {};
    #pragma unroll
    for (int kc = 0; kc < 4; kc++) {
        bf16x8 xf = *(const bf16x8*)&SLAB[((kc * 4 + quad) * 16 + mm) * 8];
        #pragma unroll
        for (int nt = 0; nt < 8; nt++) {
            bf16x8 wu = *(const bf16x8*)(wrb + (size_t)(nt * 16 + mm) * 128 + kc * 32 + quad * 8);
            bf16x8 wvv = *(const bf16x8*)(wsb + (size_t)(nt * 16 + mm) * 128 + kc * 32 + quad * 8);
            ua[nt] = MFMA(wu, xf, ua[nt]);
            va[nt] = MFMA(wvv, xf, va[nt]);
        }
    }
    #pragma unroll
    for (int nt = 0; nt < 8; nt++)
        *(uint2*)&SLAB[mm * 136 + nt * 16 + quad * 4] = pv[nt];
    slab_flush16(SLAB, lane, effb + wrow);
    slab_write_rows(SLAB, mm, quad, ua, (const float*)0);
    slab_flush16(SLAB, lane, Uo + wrow);
    slab_write_rows(SLAB, mm, quad, va, (const float*)0);
    slab_flush16(SLAB, lane, Vo + wrow);
}

// ================= pooled mean =================
__global__ __launch_bounds__(256) void k_pool(const u16* __restrict__ effb,
                                              float* __restrict__ pooled) {
    int f = blockIdx.x;
    __shared__ float red[256];
    float s = 0.f;
    for (int r = threadIdx.x; r < RIG_; r += 256) s += b2f(effb[(size_t)r * 128 + f]);
    red[threadIdx.x] = s; __syncthreads();
    for (int o = 128; o > 0; o >>= 1) {
        if (threadIdx.x < o) red[threadIdx.x] += red[threadIdx.x + o];
        __syncthreads();
    }
    if (threadIdx.x == 0) pooled[f] = red[0] / (float)RIG_;
}

// ================= rigid head =================
__global__ __launch_bounds__(128) void k_rigid_head(
        const float* __restrict__ pooled,
        const float* __restrict__ w0, const float* __restrict__ b0,
        const float* __restrict__ w1, const float* __restrict__ b1,
        const float* __restrict__ w2, const float* __restrict__ b2,
        float* __restrict__ rig) {
    __shared__ float pl[128], ha[128], hb[128], tv[7];
    int t = threadIdx.x;
    pl[t] = pooled[t];
    __syncthreads();
    float a = b0[t];
    for (int k = 0; k < 128; k++) a += w0[t * 128 + k] * pl[k];
    ha[t] = fmaxf(a, 0.f);
    __syncthreads();
    a = b1[t];
    for (int k = 0; k < 128; k++) a += w1[t * 128 + k] * ha[k];
    hb[t] = fmaxf(a, 0.f);
    __syncthreads();
    if (t < 7) {
        float s = b2[t];
        for (int k = 0; k < 128; k++) s += w2[t * 128 + k] * hb[k];
        tv[t] = s;
    }
    __syncthreads();
    if (t == 0) {
        float w = tv[0], x = tv[1], y = tv[2], z = tv[3];
        float n = sqrtf(w * w + x * x + y * y + z * z);
        w /= n; x /= n; y /= n; z /= n;
        rig[0] = 1.f - 2.f * (y * y + z * z); rig[1] = 2.f * (x * y + z * w); rig[2] = 2.f * (x * z - y * w);
        rig[3] = 2.f * (x * y - z * w); rig[4] = 1.f - 2.f * (x * x + z * z); rig[5] = 2.f * (y * z + x * w);
        rig[6] = 2.f * (x * z + y * w); rig[7] = 2.f * (y * z - x * w); rig[8] = 1.f - 2.f * (x * x + y * y);
        rig[9] = tv[4]; rig[10] = tv[5]; rig[11] = tv[6];
    }
}

// ================= rigid output =================
__global__ __launch_bounds__(256) void k_rigid_out(
        const float* __restrict__ state, const float* __restrict__ cent,
        const float* __restrict__ rig, float* __restrict__ out) {
    int i = blockIdx.x * 256 + threadIdx.x;
    if (i >= RIG_) return;
    float p0[3], d[3];
    #pragma unroll
    for (int k = 0; k < 3; k++) { p0[k] = state[i * 6 + k]; d[k] = p0[k] - cent[k]; }
    #pragma unroll
    for (int j = 0; j < 3; j++) {
        float p1 = rig[0 * 3 + j] * d[0] + rig[1 * 3 + j] * d[1] + rig[2 * 3 + j] * d[2]
                 + rig[9 + j] + cent[j];
        out[i * 3 + j] = (p1 - p0[j]) * 60.0f;
    }
}

// ================= fluid: 128 -> 128 -> 128 -> 3 =================
__global__ __launch_bounds__(256, 4) void k_fluid(
        const u16* __restrict__ effb,
        const u16* __restrict__ w0b, const float* __restrict__ b0,
        const u16* __restrict__ w1b, const float* __restrict__ b1,
        const u16* __restrict__ w2b, const float* __restrict__ b2,
        float* __restrict__ out) {
    __shared__ __align__(16) u16 BUF[4 * SLABN];
    int t = threadIdx.x;
    long base = RIG_ + (long)blockIdx.x * 64;
    int wv = t >> 6, lane = t & 63, mm = lane & 15, quad = lane >> 4;
    u16* SLAB = BUF + wv * SLABN;
    long node = base + wv * 16 + mm;
    #pragma unroll
    for (int i = 0; i < 4; i++) {
        int kq = quad + 4 * i;
        *(uint4*)&SLAB[(kq * 16 + mm) * 8] =
            *(const uint4*)(effb + node * 128 + kq * 8);
    }
    layer_inplace(SLAB, mm, quad, w0b, b0);
    layer_inplace(SLAB, mm, quad, w1b, b1);
    {
        f32x4 acc = {};
        #pragma unroll
        for (int kc = 0; kc < 4; kc++) {
            bf16x8 xf = *(const bf16x8*)&SLAB[((kc * 4 + quad) * 16 + mm) * 8];
            bf16x8 wf = *(const bf16x8*)(w2b + (size_t)mm * 128 + kc * 32 + quad * 8);
            acc = MFMA(wf, xf, acc);
        }
        if (quad == 0) {
            #pragma unroll
            for (int rg = 0; rg < 3; rg++)
                out[node * 3 + rg] = acc[rg] + b2[rg];
        }
    }
}

// ================= host =================
extern "C" void kernel_launch(void* const* d_in, const int* in_sizes, int n_in,
                              void* d_out, int out_size, void* d_ws, size_t ws_size,
                              hipStream_t stream) {
    const float* state = (const float*)d_in[0];
    const float* attr  = (const float*)d_in[1];
    const float* Ra    = (const float*)d_in[2];
    const int*   recv  = (const int*)d_in[3];
    const int*   send  = (const int*)d_in[4];
    const float* pe_w0 = (const float*)d_in[5];  const float* pe_b0 = (const float*)d_in[6];
    const float* pe_w1 = (const float*)d_in[7];  const float* pe_b1 = (const float*)d_in[8];
    const float* re_w0 = (const float*)d_in[9];  const float* re_b0 = (const float*)d_in[10];
    const float* re_w1 = (const float*)d_in[11]; const float* re_b1 = (const float*)d_in[12];
    const float* re_w2 = (const float*)d_in[13]; const float* re_b2 = (const float*)d_in[14];
    const float* rp_w  = (const float*)d_in[15]; const float* rp_b  = (const float*)d_in[16];
    const float* pp_w  = (const float*)d_in[17]; const float* pp_b  = (const float*)d_in[18];
    const float* rg_w0 = (const float*)d_in[19]; const float* rg_b0 = (const float*)d_in[20];
    const float* rg_w1 = (const float*)d_in[21]; const float* rg_b1 = (const float*)d_in[22];
    const float* rg_w2 = (const float*)d_in[23]; const float* rg_b2 = (const float*)d_in[24];
    const float* fl_w0 = (const float*)d_in[25]; const float* fl_b0 = (const float*)d_in[26];
    const float* fl_w1 = (const float*)d_in[27]; const float* fl_b1 = (const float*)d_in[28];
    const float* fl_w2 = (const float*)d_in[29]; const float* fl_b2 = (const float*)d_in[30];
    float* out = (float*)d_out;

    char* p = (char*)d_ws;
    auto alloc = [&](size_t bytes) { char* r = p; p += (bytes + 255) / 256 * 256; return r; };
    float* cent    = (float*)alloc(8 * 4);
    float* pooled  = (float*)alloc(128 * 4);
    float* rig     = (float*)alloc(16 * 4);
    u32*   rowhead = (u32*)alloc((size_t)N_P * 4);
    u32*   rowptr  = (u32*)alloc(((size_t)N_P + 1) * 4);
    u32*   bsum    = (u32*)alloc(256 * 4);
    float* sra     = (float*)alloc((size_t)N_E * 4);
    int*   srecv   = (int*)alloc((size_t)N_E * 4);
    int*   ssend   = (int*)alloc((size_t)N_E * 4);
    u16*   Z       = (u16*)alloc((size_t)N_E * 128 * 2);
    u16*   effb    = (u16*)alloc((size_t)N_P * 128 * 2);
    u16*   T       = (u16*)alloc((size_t)N_P * 128 * 2);
    u16*   P       = (u16*)alloc((size_t)N_P * 128 * 2);   // aliased as U after k_rel
    u16*   Q       = (u16*)alloc((size_t)N_P * 128 * 2);   // aliased as V after k_rel
    u16*   wreb    = (u16*)alloc(128 * 128 * 2);
    u16*   wrb     = (u16*)alloc(128 * 128 * 2);
    u16*   wsb     = (u16*)alloc(128 * 128 * 2);
    u16*   wpb     = (u16*)alloc(128 * 128 * 2);
    u16*   wab     = (u16*)alloc(128 * 128 * 2);
    u16*   rw1b    = (u16*)alloc(128 * 128 * 2);
    u16*   rw2b    = (u16*)alloc(128 * 128 * 2);
    u16*   pew1b   = (u16*)alloc(128 * 128 * 2);
    u16*   flw0b   = (u16*)alloc(128 * 128 * 2);
    u16*   flw1b   = (u16*)alloc(128 * 128 * 2);
    u16*   flw2b   = (u16*)alloc(16 * 128 * 2);
    u16*   w0rb    = (u16*)alloc(128 * 32 * 2);
    u16*   w0sb    = (u16*)alloc(128 * 32 * 2);
    u16*   pew0b   = (u16*)alloc(128 * 32 * 2);
    u16*   wRab    = (u16*)alloc(128 * 2);
    size_t need = (size_t)(p - (char*)d_ws);
    if (ws_size < need) {
        fprintf(stderr, "kernel_launch: ws_size %zu < needed %zu\n", ws_size, need);
        return;
    }
    u16* U = P; u16* V = Q;

    // sort edges by recv (also builds CSR rowptr; permutes Ra)
    hipMemsetAsync(rowhead, 0, (size_t)N_P * 4, stream);
    k_hist<<<N_E / 256, 256, 0, stream>>>(recv, rowhead);
    k_scan1<<<N_P / 256, 256, 0, stream>>>(rowhead, bsum);
    k_scan2<<<1, 256, 0, stream>>>(bsum);
    k_scan3<<<N_P / 256, 256, 0, stream>>>(rowhead, bsum, rowptr);
    k_scatter<<<N_E / 256, 256, 0, stream>>>(recv, send, Ra, rowhead, srecv, ssend, sra);

    // weight conversion
    CvtArgs ca;
    int bs = 0;
    auto addjob = [&](int idx, const float* s, u16* d, int n, int mode) {
        ca.j[idx] = {s, d, n, mode, bs};
        bs += (n + 255) / 256;
    };
    addjob(0,  rp_w,        wreb,  128 * 128, 3);
    addjob(1,  rp_w + 128,  wrb,   128 * 128, 3);
    addjob(2,  rp_w + 256,  wsb,   128 * 128, 3);
    addjob(3,  pp_w,        wpb,   128 * 128, 4);
    addjob(4,  pp_w + 128,  wab,   128 * 128, 4);
    addjob(5,  re_w1,       rw1b,  128 * 128, 0);
    addjob(6,  re_w2,       rw2b,  128 * 128, 0);
    addjob(7,  pe_w1,       pew1b, 128 * 128, 0);
    addjob(8,  fl_w0,       flw0b, 128 * 128, 0);
    addjob(9,  fl_w1,       flw1b, 128 * 128, 0);
    addjob(10, fl_w2,       flw2b, 16 * 128,  2);
    addjob(11, re_w0,       w0rb,  128 * 32,  5);
    addjob(12, re_w0,       w0sb,  128 * 32,  6);
    addjob(13, pe_w0,       pew0b, 128 * 32,  7);
    addjob(14, re_w0,       wRab,  128,       8);
    k_cvt_all<<<bs, 256, 0, stream>>>(ca);

    // encoders
    k_centroid<<<6, 256, 0, stream>>>(state, cent);
    k_particle_ext<<<N_P / 64, 256, 0, stream>>>(state, attr, cent,
                                                 w0rb, w0sb, re_b0, pew0b, pe_b0,
                                                 pew1b, pe_b1, wpb, P, Q, T);

    // relation encoder -> Z
    k_rel<<<N_E / 64, 256, 0, stream>>>(P, Q, sra, srecv, ssend, wRab,
                                        rw1b, re_b1, rw2b, re_b2, wreb, Z);

    // propagation steps (node-parallel CSR, no atomics)
    k_step<<<N_P / 64, 256, 0, stream>>>(Z, ssend, rowptr, U, V, rp_b,
                                         T, wab, pp_b, wrb, wsb, effb, U, V, 1);
    k_step<<<N_P / 64, 256, 0, stream>>>(Z, ssend, rowptr, U, V, rp_b,
                                         T, wab, pp_b, wrb, wsb, effb, U, V, 2);

    // heads
    k_pool<<<128, 256, 0, stream>>>(effb, pooled);
    k_rigid_head<<<1, 128, 0, stream>>>(pooled, rg_w0, rg_b0, rg_w1, rg_b1, rg_w2, rg_b2, rig);
    k_rigid_out<<<(RIG_ + 255) / 256, 256, 0, stream>>>(state, cent, rig, out);
    k_fluid<<<(N_P - RIG_) / 64, 256, 0, stream>>>(effb, flw0b, fl_b0, flw1b, fl_b1,
                                                   flw2b, fl_b2, out);
}